// Round 15
// baseline (37.432 us; speedup 1.0000x reference)
//
#include <hip/hip_runtime.h>
#include <hip/hip_bf16.h>
#include <math.h>

#define NB 8
#define ND 64
#define NS 512

typedef __attribute__((ext_vector_type(8))) short bf16x8;
typedef __attribute__((ext_vector_type(4))) float f32x4;
typedef __attribute__((ext_vector_type(4))) unsigned short us4;
typedef __attribute__((ext_vector_type(4))) unsigned int u32x4;

__device__ __forceinline__ unsigned int pk2(float lo, float hi) {
    __hip_bfloat162 h = __float22bfloat162_rn(make_float2(lo, hi));   // v_cvt_pk_bf16_f32
    unsigned int u;
    __builtin_memcpy(&u, &h, 4);
    return u;
}
__device__ __forceinline__ unsigned short f2bf_s(float f) {
    __hip_bfloat16 h = __float2bfloat16(f);
    unsigned short u;
    __builtin_memcpy(&u, &h, 2);
    return u;
}

#define MFMA __builtin_amdgcn_mfma_f32_16x16x32_bf16

// ---------------------------------------------------------------------------
// Kernel 1 (R14-validated): per (b, j-tile of 64): a/b rows via MFMA,
// norms, x->bf16 natural layout. 64 blocks x 256 threads.
// ---------------------------------------------------------------------------
__global__ __launch_bounds__(256) void k_prep(const float* __restrict__ x,
                                              const float* __restrict__ W,
                                              unsigned short* __restrict__ a_bf,
                                              unsigned short* __restrict__ b_bf,
                                              float* __restrict__ na,
                                              float* __restrict__ nb,
                                              unsigned short* __restrict__ x_bf) {
    __shared__ __align__(16) unsigned short xT[64 * 64];    // [j][d] swz
    __shared__ __align__(16) unsigned short WT[128 * 64];   // [n][d] swz

    int b  = blockIdx.y;
    int j0 = blockIdx.x * 64;
    int t  = threadIdx.x;
    int lane = t & 63, wv = t >> 6, c = lane & 15, g = lane >> 4, c7 = c & 7;
    int wl = t & 63, w2 = t >> 6;

    // stage xT[j][d] (transposed scalar loads, validated)
    float xi_[16];
#pragma unroll
    for (int j = 0; j < 2; ++j)
#pragma unroll
        for (int e = 0; e < 8; ++e) {
            int d = 8 * (2 * w2 + j) + e;
            xi_[8 * j + e] = x[((size_t)(b * ND) + d) * NS + j0 + wl];
        }
#pragma unroll
    for (int j = 0; j < 2; ++j) {
        int dblk = 2 * w2 + j;
        u32x4 h;
#pragma unroll
        for (int e = 0; e < 4; ++e)
            h[e] = pk2(xi_[8 * j + 2 * e], xi_[8 * j + 2 * e + 1]);
        *(u32x4*)&xT[wl * 64 + ((dblk ^ (wl & 7)) << 3)] = h;
    }
    // stage WT[n][d] (validated)
    {
        int n = t & 127, half = t >> 7;
        float wv_[32];
#pragma unroll
        for (int p = 0; p < 4; ++p)
#pragma unroll
            for (int dd = 0; dd < 8; ++dd) {
                int dg = half * 4 + p;
                wv_[8 * p + dd] =
                    W[(size_t)(dg * 8 + dd) * ND + (n & 63) + ((n >> 6) * (ND * ND))];
            }
#pragma unroll
        for (int p = 0; p < 4; ++p) {
            int dg = half * 4 + p;
            u32x4 h;
#pragma unroll
            for (int dd = 0; dd < 4; ++dd)
                h[dd] = pk2(wv_[8 * p + 2 * dd], wv_[8 * p + 2 * dd + 1]);
            *(u32x4*)&WT[n * 64 + ((dg ^ (n & 7)) << 3)] = h;
        }
    }
    // x -> x_bf (natural [d][j] layout, coalesced stores)
#pragma unroll
    for (int q = 0; q < 2; ++q) {
        int e = t + 256 * q;
        int d = e >> 3, wc = e & 7;
        const float4* p4 = (const float4*)(x + ((size_t)(b * ND) + d) * NS + j0 + 8 * wc);
        float4 v0 = p4[0], v1 = p4[1];
        u32x4 h;
        h[0] = pk2(v0.x, v0.y); h[1] = pk2(v0.z, v0.w);
        h[2] = pk2(v1.x, v1.y); h[3] = pk2(v1.z, v1.w);
        *(u32x4*)(x_bf + ((size_t)(b * ND) + d) * NS + j0 + 8 * wc) = h;
    }
    __syncthreads();

    // phase A: a/b via MFMA (validated)
    f32x4 aacc[4] = {{0,0,0,0},{0,0,0,0},{0,0,0,0},{0,0,0,0}};
    f32x4 bacc[4] = {{0,0,0,0},{0,0,0,0},{0,0,0,0},{0,0,0,0}};
#pragma unroll
    for (int ks = 0; ks < 2; ++ks) {
        int row = 16 * wv + c;
        bf16x8 P = *(const bf16x8*)&xT[row * 64 + (((4 * ks + g) ^ c7) << 3)];
#pragma unroll
        for (int qb = 0; qb < 4; ++qb) {
            bf16x8 Qw = *(const bf16x8*)&WT[(16 * qb + c) * 64 + (((4 * ks + g) ^ c7) << 3)];
            bf16x8 Qh = *(const bf16x8*)&WT[(64 + 16 * qb + c) * 64 + (((4 * ks + g) ^ c7) << 3)];
            aacc[qb] = MFMA(P, Qw, aacc[qb], 0, 0, 0);
            bacc[qb] = MFMA(P, Qh, bacc[qb], 0, 0, 0);
        }
    }
    // norms -> global (validated)
#pragma unroll
    for (int r = 0; r < 4; ++r) {
        float sa = aacc[0][r] * aacc[0][r] + aacc[1][r] * aacc[1][r]
                 + aacc[2][r] * aacc[2][r] + aacc[3][r] * aacc[3][r];
        float sb = bacc[0][r] * bacc[0][r] + bacc[1][r] * bacc[1][r]
                 + bacc[2][r] * bacc[2][r] + bacc[3][r] * bacc[3][r];
        sa += __shfl_xor(sa, 1, 64); sa += __shfl_xor(sa, 2, 64);
        sa += __shfl_xor(sa, 4, 64); sa += __shfl_xor(sa, 8, 64);
        sb += __shfl_xor(sb, 1, 64); sb += __shfl_xor(sb, 2, 64);
        sb += __shfl_xor(sb, 4, 64); sb += __shfl_xor(sb, 8, 64);
        if (c == 0) {
            na[b * NS + j0 + 16 * wv + 4 * g + r] = sa;
            nb[b * NS + j0 + 16 * wv + 4 * g + r] = sb;
        }
    }
    // a_bf/b_bf stores (validated)
#pragma unroll
    for (int qb = 0; qb < 4; ++qb)
#pragma unroll
        for (int r = 0; r < 4; ++r) {
            int row = 16 * wv + 4 * g + r, k = 16 * qb + c;
            size_t off = ((size_t)b * NS + j0 + row) * ND + k;
            a_bf[off] = f2bf_s(aacc[qb][r]);
            b_bf[off] = f2bf_s(bacc[qb][r]);
        }
}

// ---------------------------------------------------------------------------
// Kernel 2: block (b, ti) owns out[b,:,64ti..64ti+63]. Loops u=ti..7 with
// REGISTER accumulation (no part buffer): per u, GEMM1 -> wm -> GEMM2 into
// cacc. Epilogue adds rowsum(x) and stores out. All patterns from R14 k_c.
// ---------------------------------------------------------------------------
__global__ __launch_bounds__(256) void k_main(const float* __restrict__ x,
                                              const unsigned short* __restrict__ x_bf,
                                              const unsigned short* __restrict__ a_bf,
                                              const unsigned short* __restrict__ b_bf,
                                              const float* __restrict__ na,
                                              const float* __restrict__ nb,
                                              float* __restrict__ out) {
    __shared__ unsigned short wm_lds[64 * 64];
    __shared__ float rs_lds[64];

    int b  = blockIdx.y;
    int ti = blockIdx.x;
    int i0 = ti * 64;
    int t = threadIdx.x;
    int lane = t & 63, wv = t >> 6;
    int c = lane & 15, g = lane >> 4;

    // rowsum rs[d] (R7-validated 4-lane pattern): d = t>>2, quarter = t&3
    {
        const float* xr = x + ((size_t)(b * ND) + (t >> 2)) * NS + (t & 3) * 128;
        float s = 0.f;
#pragma unroll
        for (int e = 0; e < 32; ++e) {
            float4 v = *(const float4*)(xr + 4 * e);
            s += v.x + v.y + v.z + v.w;
        }
        s += __shfl_xor(s, 1, 64);
        s += __shfl_xor(s, 2, 64);
        if ((t & 3) == 0) rs_lds[t >> 2] = s;
    }

    // fixed fragments: a-rows of this i-tile (GEMM1 B-operand) + na
    bf16x8 bfrag[4][2];
#pragma unroll
    for (int n = 0; n < 4; ++n) {
        const unsigned short* aa = a_bf + ((size_t)(b * NS + i0 + 16 * n + c)) * ND + g * 8;
        bfrag[n][0] = *(const bf16x8*)(aa);
        bfrag[n][1] = *(const bf16x8*)(aa + 32);
    }
    float nav[4];
#pragma unroll
    for (int n = 0; n < 4; ++n) nav[n] = na[b * NS + i0 + 16 * n + c];

    f32x4 cacc[4] = {{0.f,0.f,0.f,0.f},{0.f,0.f,0.f,0.f},{0.f,0.f,0.f,0.f},{0.f,0.f,0.f,0.f}};

    for (int u = ti; u < 8; ++u) {
        int w0 = u * 64;
        __syncthreads();   // prev-iter wm_lds readers done (1st iter: also covers rs staging)

        // per-u loads: b-rows (GEMM1 A-operand), x-fragments, nb
        bf16x8 afrag[2], xfrag[4][2];
        {
            const unsigned short* bb = b_bf + ((size_t)(b * NS + w0 + 16 * wv + c)) * ND + g * 8;
            afrag[0] = *(const bf16x8*)(bb);
            afrag[1] = *(const bf16x8*)(bb + 32);
        }
#pragma unroll
        for (int nd = 0; nd < 4; ++nd) {
            const unsigned short* xx = x_bf + ((size_t)(b * ND + 16 * nd + c)) * NS + w0 + 8 * g;
            xfrag[nd][0] = *(const bf16x8*)(xx);
            xfrag[nd][1] = *(const bf16x8*)(xx + 32);
        }
        float nbv[4];
#pragma unroll
        for (int r = 0; r < 4; ++r) nbv[r] = nb[b * NS + w0 + 16 * wv + 4 * g + r];

        // GEMM1 + wm -> LDS (validated)
        int wbase = w0 + 16 * wv + 4 * g;
#pragma unroll
        for (int n = 0; n < 4; ++n) {
            f32x4 acc = {0.f, 0.f, 0.f, 0.f};
            acc = MFMA(afrag[0], bfrag[n][0], acc, 0, 0, 0);
            acc = MFMA(afrag[1], bfrag[n][1], acc, 0, 0, 0);
            int i_loc  = 16 * n + c;
            int i_glob = i0 + i_loc;
            float vals[4];
#pragma unroll
            for (int r = 0; r < 4; ++r) {
                float s2 = nav[n] + nbv[r] + 2.f * acc[r];
                vals[r] = (i_glob <= wbase + r) ? -sqrtf(fmaxf(s2, 0.f)) : 0.f;
            }
            us4 pk;
            pk[0] = f2bf_s(vals[0]); pk[1] = f2bf_s(vals[1]);
            pk[2] = f2bf_s(vals[2]); pk[3] = f2bf_s(vals[3]);
            int wblk = 2 * wv + (g >> 1);
            int hidx = i_loc * 64 + ((wblk ^ (i_loc & 7)) << 3) + 4 * (g & 1);
            *(us4*)(&wm_lds[hidx]) = pk;
        }
        __syncthreads();

        // GEMM2: accumulate into cacc (validated pattern, acc chained)
        bf16x8 a2[2];
        {
            int il = 16 * wv + c;
#pragma unroll
            for (int s = 0; s < 2; ++s)
                a2[s] = *(const bf16x8*)(&wm_lds[il * 64 + (((4 * s + g) ^ (il & 7)) << 3)]);
        }
#pragma unroll
        for (int nd = 0; nd < 4; ++nd) {
            cacc[nd] = MFMA(a2[0], xfrag[nd][0], cacc[nd], 0, 0, 0);
            cacc[nd] = MFMA(a2[1], xfrag[nd][1], cacc[nd], 0, 0, 0);
        }
    }

    // epilogue: out[b][d][i0+16wv+4g+r] = cacc + rs[d]  (R7-validated)
#pragma unroll
    for (int nd = 0; nd < 4; ++nd) {
        int d = 16 * nd + c;
        float rsv = rs_lds[d];
        f32x4 o = cacc[nd];
        o[0] += rsv; o[1] += rsv; o[2] += rsv; o[3] += rsv;
        *(f32x4*)(out + ((size_t)(b * ND) + d) * NS + i0 + 16 * wv + 4 * g) = o;
    }
}

extern "C" void kernel_launch(void* const* d_in, const int* in_sizes, int n_in,
                              void* d_out, int out_size, void* d_ws, size_t ws_size,
                              hipStream_t stream) {
    const float* x = (const float*)d_in[0];
    const float* W = (const float*)d_in[1];
    float* out = (float*)d_out;

    unsigned short* a_bf = (unsigned short*)d_ws;            // 512 KB
    unsigned short* b_bf = a_bf + (size_t)NB * NS * ND;      // 512 KB
    unsigned short* x_bf = b_bf + (size_t)NB * NS * ND;      // 512 KB
    float* na_p = (float*)(x_bf + (size_t)NB * NS * ND);     // 16 KB
    float* nb_p = na_p + NB * NS;                            // 16 KB

    k_prep<<<dim3(NS / 64, NB), dim3(256), 0, stream>>>(x, W, a_bf, b_bf, na_p, nb_p, x_bf);
    k_main<<<dim3(8, NB),       dim3(256), 0, stream>>>(x, x_bf, a_bf, b_bf, na_p, nb_p, out);
}

// Round 16
// 17.512 us; speedup vs baseline: 2.1375x; 2.1375x over previous
//
#include <hip/hip_runtime.h>
#include <hip/hip_bf16.h>
#include <math.h>

#define NB 8
#define ND 64
#define NS 512

typedef __attribute__((ext_vector_type(8))) short bf16x8;
typedef __attribute__((ext_vector_type(4))) float f32x4;
typedef __attribute__((ext_vector_type(4))) unsigned short us4;
typedef __attribute__((ext_vector_type(2))) unsigned int u32x2;
typedef __attribute__((ext_vector_type(4))) unsigned int u32x4;

__device__ __forceinline__ unsigned int pk2(float lo, float hi) {
    __hip_bfloat162 h = __float22bfloat162_rn(make_float2(lo, hi));   // v_cvt_pk_bf16_f32
    unsigned int u;
    __builtin_memcpy(&u, &h, 4);
    return u;
}
__device__ __forceinline__ unsigned short f2bf_s(float f) {
    __hip_bfloat16 h = __float2bfloat16(f);
    unsigned short u;
    __builtin_memcpy(&u, &h, 2);
    return u;
}

#define MFMA __builtin_amdgcn_mfma_f32_16x16x32_bf16

// ---------------------------------------------------------------------------
// Kernel 1 (R11-validated structure, staging loops ROLLED to cut code size):
// self-contained part-tile compute. Block (b, v=(ti,u), ti<=u), 256 threads.
// ---------------------------------------------------------------------------
__global__ __launch_bounds__(256, 2) void k_part(const float* __restrict__ x,
                                                 const float* __restrict__ W,
                                                 float* __restrict__ part) {
    __shared__ __align__(16) unsigned short WT[128 * 64];
    __shared__ __align__(16) unsigned short xwd_i[64 * 64];
    __shared__ __align__(16) unsigned short xwd_u[64 * 64];
    __shared__ __align__(16) unsigned short xdw[64 * 64];
    __shared__ __align__(16) unsigned short alds[64 * 64];
    __shared__ __align__(16) unsigned short blds[64 * 64];
    __shared__ __align__(16) unsigned short wmb[64 * 64];
    __shared__ float na_lds[64], nb_lds[64];

    int b = blockIdx.y;
    int v = blockIdx.x;
    int u = 0;
    while ((u + 1) * (u + 2) / 2 <= v) ++u;   // w-tile
    int ti = v - u * (u + 1) / 2;             // i-tile (ti <= u)
    int i0 = ti * 64, w0 = u * 64;

    int t = threadIdx.x;
    int lane = t & 63, wv = t >> 6, c = lane & 15, g = lane >> 4, c7 = c & 7;
    int wl = t & 63, w2 = t >> 6;

    // ---- staging: x transposed tiles (rolled j-loop) ----
#pragma unroll 1
    for (int j = 0; j < 2; ++j) {
        int dblk = 2 * w2 + j;
        float vi[8], vu[8];
#pragma unroll
        for (int e = 0; e < 8; ++e) {
            const float* base = x + ((size_t)(b * ND) + 8 * dblk + e) * NS;
            vi[e] = base[i0 + wl];
            vu[e] = base[w0 + wl];
        }
        u32x4 hi, hu;
#pragma unroll
        for (int e = 0; e < 4; ++e) {
            hi[e] = pk2(vi[2 * e], vi[2 * e + 1]);
            hu[e] = pk2(vu[2 * e], vu[2 * e + 1]);
        }
        *(u32x4*)&xwd_i[wl * 64 + ((dblk ^ (wl & 7)) << 3)] = hi;
        *(u32x4*)&xwd_u[wl * 64 + ((dblk ^ (wl & 7)) << 3)] = hu;
    }
    // ---- staging: xdw [d][w] (rolled q-loop, coalesced f32x4) ----
#pragma unroll 1
    for (int q = 0; q < 2; ++q) {
        int e = t + 256 * q;
        int d = e >> 3, wc = e & 7;
        const float4* p4 = (const float4*)(x + ((size_t)(b * ND) + d) * NS + w0 + 8 * wc);
        float4 v0 = p4[0], v1 = p4[1];
        u32x4 h;
        h[0] = pk2(v0.x, v0.y); h[1] = pk2(v0.z, v0.w);
        h[2] = pk2(v1.x, v1.y); h[3] = pk2(v1.z, v1.w);
        *(u32x4*)&xdw[d * 64 + ((wc ^ (d & 7)) << 3)] = h;
    }
    // ---- staging: W -> WT (rolled p-loop) ----
    {
        int n = t & 127, half = t >> 7;
#pragma unroll 1
        for (int p = 0; p < 4; ++p) {
            int dg = half * 4 + p;
            float wv_[8];
#pragma unroll
            for (int dd = 0; dd < 8; ++dd)
                wv_[dd] = W[(size_t)(dg * 8 + dd) * ND + (n & 63) + ((n >> 6) * (ND * ND))];
            u32x4 h;
#pragma unroll
            for (int dd = 0; dd < 4; ++dd)
                h[dd] = pk2(wv_[2 * dd], wv_[2 * dd + 1]);
            *(u32x4*)&WT[n * 64 + ((dg ^ (n & 7)) << 3)] = h;
        }
    }
    __syncthreads();

    // ---- a-GEMM and b-GEMM (validated, unrolled) ----
    {
        f32x4 aacc[4] = {{0,0,0,0},{0,0,0,0},{0,0,0,0},{0,0,0,0}};
        f32x4 bacc[4] = {{0,0,0,0},{0,0,0,0},{0,0,0,0},{0,0,0,0}};
#pragma unroll
        for (int ks = 0; ks < 2; ++ks) {
            int row = 16 * wv + c;
            bf16x8 Pi = *(const bf16x8*)&xwd_i[row * 64 + (((4 * ks + g) ^ c7) << 3)];
            bf16x8 Pu = *(const bf16x8*)&xwd_u[row * 64 + (((4 * ks + g) ^ c7) << 3)];
#pragma unroll
            for (int qb = 0; qb < 4; ++qb) {
                bf16x8 Qw = *(const bf16x8*)&WT[(16 * qb + c) * 64 + (((4 * ks + g) ^ c7) << 3)];
                bf16x8 Qh = *(const bf16x8*)&WT[(64 + 16 * qb + c) * 64 + (((4 * ks + g) ^ c7) << 3)];
                aacc[qb] = MFMA(Pi, Qw, aacc[qb], 0, 0, 0);
                bacc[qb] = MFMA(Pu, Qh, bacc[qb], 0, 0, 0);
            }
        }
#pragma unroll
        for (int r = 0; r < 4; ++r) {
            float sa = aacc[0][r] * aacc[0][r] + aacc[1][r] * aacc[1][r]
                     + aacc[2][r] * aacc[2][r] + aacc[3][r] * aacc[3][r];
            float sb = bacc[0][r] * bacc[0][r] + bacc[1][r] * bacc[1][r]
                     + bacc[2][r] * bacc[2][r] + bacc[3][r] * bacc[3][r];
            sa += __shfl_xor(sa, 1, 64); sa += __shfl_xor(sa, 2, 64);
            sa += __shfl_xor(sa, 4, 64); sa += __shfl_xor(sa, 8, 64);
            sb += __shfl_xor(sb, 1, 64); sb += __shfl_xor(sb, 2, 64);
            sb += __shfl_xor(sb, 4, 64); sb += __shfl_xor(sb, 8, 64);
            if (c == 0) {
                na_lds[16 * wv + 4 * g + r] = sa;
                nb_lds[16 * wv + 4 * g + r] = sb;
            }
        }
#pragma unroll
        for (int qb = 0; qb < 4; ++qb)
#pragma unroll
            for (int r = 0; r < 4; ++r) {
                int row = 16 * wv + 4 * g + r, k = 16 * qb + c;
                int off = row * 64 + (((k >> 3) ^ (row & 7)) << 3) + (k & 7);
                alds[off] = f2bf_s(aacc[qb][r]);
                blds[off] = f2bf_s(bacc[qb][r]);
            }
    }
    __syncthreads();

    // ---- GEMM1: S[w][i] = b·a^T ; wm = masked -sqrt(na+nb+2S) (validated) ----
    {
        int wrow = 16 * wv + c;
        bf16x8 P0 = *(const bf16x8*)&blds[wrow * 64 + ((g ^ c7) << 3)];
        bf16x8 P1 = *(const bf16x8*)&blds[wrow * 64 + (((4 + g) ^ c7) << 3)];
        float nbv[4];
#pragma unroll
        for (int r = 0; r < 4; ++r) nbv[r] = nb_lds[16 * wv + 4 * g + r];
        int wbase = w0 + 16 * wv + 4 * g;
#pragma unroll
        for (int n = 0; n < 4; ++n) {
            int arow = 16 * n + c;
            f32x4 a1 = {0.f, 0.f, 0.f, 0.f};
            bf16x8 Q0 = *(const bf16x8*)&alds[arow * 64 + ((g ^ c7) << 3)];
            bf16x8 Q1 = *(const bf16x8*)&alds[arow * 64 + (((4 + g) ^ c7) << 3)];
            a1 = MFMA(P0, Q0, a1, 0, 0, 0);
            a1 = MFMA(P1, Q1, a1, 0, 0, 0);
            float navv = na_lds[arow];
            int i_glob = i0 + arow;
            float vals[4];
#pragma unroll
            for (int r = 0; r < 4; ++r) {
                float s2v = navv + nbv[r] + 2.f * a1[r];
                vals[r] = (i_glob <= wbase + r) ? -sqrtf(fmaxf(s2v, 0.f)) : 0.f;
            }
            u32x2 pk;
            pk[0] = pk2(vals[0], vals[1]);
            pk[1] = pk2(vals[2], vals[3]);
            int wblk = 2 * wv + (g >> 1);
            *(u32x2*)&wmb[arow * 64 + ((wblk ^ (arow & 7)) << 3) + 4 * (g & 1)] = pk;
        }
    }
    __syncthreads();

    // ---- GEMM2: part[u][b][d][i-tile] = wm·x^T (validated) ----
    {
        int il = 16 * wv + c;
        bf16x8 a20 = *(const bf16x8*)&wmb[il * 64 + ((g ^ c7) << 3)];
        bf16x8 a21 = *(const bf16x8*)&wmb[il * 64 + (((4 + g) ^ c7) << 3)];
#pragma unroll
        for (int nd = 0; nd < 4; ++nd) {
            int d = 16 * nd + c;
            bf16x8 q0 = *(const bf16x8*)&xdw[d * 64 + ((g ^ c7) << 3)];
            bf16x8 q1 = *(const bf16x8*)&xdw[d * 64 + (((4 + g) ^ c7) << 3)];
            f32x4 acc = {0.f, 0.f, 0.f, 0.f};
            acc = MFMA(a20, q0, acc, 0, 0, 0);
            acc = MFMA(a21, q1, acc, 0, 0, 0);
            float* pp = part + (((size_t)u * NB + b) * ND + d) * NS + i0 + 16 * wv + 4 * g;
            *(f32x4*)pp = acc;
        }
    }
}

// ---------------------------------------------------------------------------
// Kernel 2 (R11-validated): out = rowsum(x) + sum part slices.
// 512 blocks x 128 threads, all-f32x4.
// ---------------------------------------------------------------------------
__global__ __launch_bounds__(128) void k_red(const float* __restrict__ x,
                                             const float* __restrict__ part,
                                             float* __restrict__ out) {
    __shared__ float red[2];
    int b = blockIdx.y, d = blockIdx.x, t = threadIdx.x;   // t < 128
    const float* xr = x + ((size_t)b * ND + d) * NS;

    float4 xv = *(const float4*)(xr + 4 * t);
    float s = xv.x + xv.y + xv.z + xv.w;
#pragma unroll
    for (int m = 32; m >= 1; m >>= 1) s += __shfl_xor(s, m, 64);
    if ((t & 63) == 0) red[t >> 6] = s;
    __syncthreads();
    float rs = red[0] + red[1];

    int it = t >> 4;
    f32x4 vv = {rs, rs, rs, rs};
#pragma unroll
    for (int u = 0; u < 8; ++u) {
        if (u >= it) {
            f32x4 pv = *(const f32x4*)&part[(((size_t)u * NB + b) * ND + d) * NS + 4 * t];
            vv[0] += pv[0]; vv[1] += pv[1]; vv[2] += pv[2]; vv[3] += pv[3];
        }
    }
    *(f32x4*)&out[((size_t)b * ND + d) * NS + 4 * t] = vv;
}

extern "C" void kernel_launch(void* const* d_in, const int* in_sizes, int n_in,
                              void* d_out, int out_size, void* d_ws, size_t ws_size,
                              hipStream_t stream) {
    const float* x = (const float*)d_in[0];
    const float* W = (const float*)d_in[1];
    float* out  = (float*)d_out;
    float* part = (float*)d_ws;                 // 8 MB

    k_part<<<dim3(36, NB), dim3(256), 0, stream>>>(x, W, part);
    k_red <<<dim3(ND, NB), dim3(128), 0, stream>>>(x, part, out);
}